// Round 15
// baseline (188.480 us; speedup 1.0000x reference)
//
#include <hip/hip_runtime.h>
#include <hip/hip_bf16.h>

// N_NODES=50000, N_EDGES=800000, IN=128, HID=128, OUT=64, fp32 in/out.
// Bucket-partitioned CSR build (atomic-free histogram) + scaled bf16
// features hs = dinv*h:  out[d] = dinv[d]*(sum hs[src] + hs[d]) + b
// GEMM: MFMA bf16 16x16x32, 64x64 tile (r12, verified).
// aggr: per-node wave, 16-edge global_load_lds chunks (r12, 43us = ~80% of
// random-gather BW ceiling; r13/r14 structural variants were neutral/worse).

#define NPB 196      // nodes per bucket
#define NBMAX 1024   // max buckets supported
#define CAP 4096     // max edges per bucket staged in LDS

using short8 = __attribute__((ext_vector_type(8))) short;
using f32x4  = __attribute__((ext_vector_type(4))) float;

__device__ __forceinline__ unsigned short f2bf(float f) {
    unsigned int u = __float_as_uint(f);
    unsigned int r = u + 0x7fffu + ((u >> 16) & 1u);   // RNE
    return (unsigned short)(r >> 16);
}

// Per-block bucket histogram: no global atomics, no init dependency.
// Block k writes its own row bhist_blk[k][0..nb).
__global__ __launch_bounds__(256) void k_bhist(const int* __restrict__ dst,
                                               int* __restrict__ bhist_blk,
                                               int nb, int e) {
    __shared__ int hist[NBMAX];
    const int tid = threadIdx.x;
    for (int b = tid; b < nb; b += 256) hist[b] = 0;
    __syncthreads();
    for (int i = blockIdx.x * 256 + tid; i < e; i += gridDim.x * 256)
        atomicAdd(&hist[dst[i] / NPB], 1);
    __syncthreads();
    for (int b = tid; b < nb; b += 256)
        bhist_blk[blockIdx.x * nb + b] = hist[b];
}

// One block: column-sum the per-block histograms, then exclusive scan.
__global__ __launch_bounds__(256) void k_bscan(const int* __restrict__ bhist_blk,
                                               int nblk,
                                               int* __restrict__ bbase,
                                               int* __restrict__ bcursor,
                                               int nb, int e) {
    __shared__ int tot[NBMAX];
    const int tid = threadIdx.x;
    for (int b = tid; b < nb; b += 256) {
        int s = 0;
        for (int k = 0; k < nblk; ++k) s += bhist_blk[k * nb + b];
        tot[b] = s;
    }
    __syncthreads();
    if (tid < 64) {
        const int lane = tid;
        int carry = 0;
        for (int base = 0; base < nb; base += 64) {
            int i = base + lane;
            int v = (i < nb) ? tot[i] : 0;
            int s = v;
#pragma unroll
            for (int d = 1; d < 64; d <<= 1) {
                int u = __shfl_up(s, d);
                if (lane >= d) s += u;
            }
            int excl = carry + s - v;
            if (i < nb) { bbase[i] = excl; bcursor[i] = excl; }
            carry += __shfl(s, 63);
        }
        if (lane == 0) bbase[nb] = e;
    }
}

// Partition edges into bucket-contiguous regions.
__global__ __launch_bounds__(256) void k_bpart(const int* __restrict__ src,
                                               const int* __restrict__ dst,
                                               int* __restrict__ bcursor,
                                               int2* __restrict__ part,
                                               int nb, int e, int cpb) {
    __shared__ int chist[NBMAX];
    __shared__ int cbase[NBMAX];
    const int tid = threadIdx.x;
    const int e0 = blockIdx.x * cpb;
    const int e1 = min(e, e0 + cpb);
    for (int b = tid; b < nb; b += 256) chist[b] = 0;
    __syncthreads();
    for (int i = e0 + tid; i < e1; i += 256)
        atomicAdd(&chist[dst[i] / NPB], 1);
    __syncthreads();
    for (int b = tid; b < nb; b += 256) {
        int c = chist[b];
        cbase[b] = c ? atomicAdd(&bcursor[b], c) : 0;
        chist[b] = 0;
    }
    __syncthreads();
    for (int i = e0 + tid; i < e1; i += 256) {
        int d = dst[i];
        int bkt = d / NPB;
        int l = atomicAdd(&chist[bkt], 1);
        part[cbase[bkt] + l] = make_int2(src[i], d);
    }
}

// One block per bucket: local counts -> local scan -> LDS-staged CSR slice.
__global__ __launch_bounds__(256) void k_bcsr(const int2* __restrict__ part,
                                              const int* __restrict__ bbase,
                                              int* __restrict__ offs,
                                              float* __restrict__ dinv,
                                              int* __restrict__ srcs,
                                              int n, int e) {
    __shared__ int cntL[256];
    __shared__ int srcsL[CAP];
    const int b = blockIdx.x;
    const int tid = threadIdx.x;
    const int eb0 = bbase[b], eb1 = bbase[b + 1];
    const int cnt = eb1 - eb0;
    const int n0 = b * NPB;
    const int npb = min(NPB, n - n0);

    if (tid < 256) cntL[tid] = 0;
    __syncthreads();
    for (int i = eb0 + tid; i < eb1; i += 256)
        atomicAdd(&cntL[part[i].y - n0], 1);
    __syncthreads();

    if (tid < 64) {
        const int lane = tid;
        int carry = 0;
        for (int base = 0; base < npb; base += 64) {
            int i = base + lane;
            int v = (i < npb) ? cntL[i] : 0;
            int s = v;
#pragma unroll
            for (int d = 1; d < 64; d <<= 1) {
                int u = __shfl_up(s, d);
                if (lane >= d) s += u;
            }
            int excl = carry + s - v;
            if (i < npb) {
                offs[n0 + i] = eb0 + excl;
                dinv[n0 + i] = rsqrtf((float)(v + 1));
                cntL[i] = excl;            // becomes the local cursor
            }
            carry += __shfl(s, 63);
        }
    }
    if (b == gridDim.x - 1 && tid == 0) offs[n] = e;
    __syncthreads();

    if (cnt <= CAP) {
        for (int i = eb0 + tid; i < eb1; i += 256) {
            int2 pr = part[i];
            int pos = atomicAdd(&cntL[pr.y - n0], 1);
            srcsL[pos] = pr.x;
        }
        __syncthreads();
        for (int i = tid; i < cnt; i += 256)
            srcs[eb0 + i] = srcsL[i];
    } else {  // safety fallback
        for (int i = eb0 + tid; i < eb1; i += 256) {
            int2 pr = part[i];
            int pos = atomicAdd(&cntL[pr.y - n0], 1);
            srcs[eb0 + pos] = pr.x;
        }
    }
}

// hs[M x Ntot] (bf16) = (A[M x 128] @ W[128 x Ntot]) * dinv[row]
// MFMA 16x16x32 bf16; 64x64 tile, 4 waves 2x2, K=128 fully staged.
template <bool SRC_BF16>
__global__ __launch_bounds__(256) void k_gemm(const void* __restrict__ A,
                                              const float* __restrict__ W,
                                              const float* __restrict__ dinv,
                                              unsigned short* __restrict__ Cout,
                                              int M, int Ntot) {
    __shared__ __align__(16) unsigned short As_b[64][136];  // [row][k]
    __shared__ __align__(16) unsigned short Bs_b[64][136];  // [col][k] (W^T)

    const int tid = threadIdx.x;
    const int bm = blockIdx.x * 64;
    const int bn = blockIdx.y * 64;

#pragma unroll
    for (int t = 0; t < 8; ++t) {
        int idx = tid + t * 256;
        int row = idx >> 5;
        int c4 = idx & 31;
        int gr = bm + row;
        ushort4 o = make_ushort4(0, 0, 0, 0);
        if (SRC_BF16) {
            if (gr < M)
                o = *(const ushort4*)&((const unsigned short*)A)[(size_t)gr * 128 + c4 * 4];
        } else {
            if (gr < M) {
                float4 f = *(const float4*)&((const float*)A)[(size_t)gr * 128 + c4 * 4];
                o = make_ushort4(f2bf(f.x), f2bf(f.y), f2bf(f.z), f2bf(f.w));
            }
        }
        *(ushort4*)&As_b[row][c4 * 4] = o;
    }

#pragma unroll
    for (int t = 0; t < 2; ++t) {
        int idx = tid + t * 256;        // 0..511
        int kb = idx >> 4;              // 0..31 -> k0 = kb*4
        int c4 = idx & 15;              // col quad
        int k0 = kb * 4;
        float4 f0 = *(const float4*)&W[(size_t)(k0 + 0) * Ntot + bn + c4 * 4];
        float4 f1 = *(const float4*)&W[(size_t)(k0 + 1) * Ntot + bn + c4 * 4];
        float4 f2 = *(const float4*)&W[(size_t)(k0 + 2) * Ntot + bn + c4 * 4];
        float4 f3 = *(const float4*)&W[(size_t)(k0 + 3) * Ntot + bn + c4 * 4];
        *(ushort4*)&Bs_b[c4 * 4 + 0][k0] =
            make_ushort4(f2bf(f0.x), f2bf(f1.x), f2bf(f2.x), f2bf(f3.x));
        *(ushort4*)&Bs_b[c4 * 4 + 1][k0] =
            make_ushort4(f2bf(f0.y), f2bf(f1.y), f2bf(f2.y), f2bf(f3.y));
        *(ushort4*)&Bs_b[c4 * 4 + 2][k0] =
            make_ushort4(f2bf(f0.z), f2bf(f1.z), f2bf(f2.z), f2bf(f3.z));
        *(ushort4*)&Bs_b[c4 * 4 + 3][k0] =
            make_ushort4(f2bf(f0.w), f2bf(f1.w), f2bf(f2.w), f2bf(f3.w));
    }
    __syncthreads();

    const int w = tid >> 6;
    const int l = tid & 63;
    const int wr = (w >> 1) * 32;
    const int wc = (w & 1) * 32;
    const int fr = l & 15;
    const int fk = (l >> 4) * 8;

    f32x4 acc[2][2] = {};

#pragma unroll
    for (int ks = 0; ks < 4; ++ks) {
        const int kof = ks * 32 + fk;
        short8 a0 = *(const short8*)&As_b[wr + fr][kof];
        short8 a1 = *(const short8*)&As_b[wr + 16 + fr][kof];
        short8 b0 = *(const short8*)&Bs_b[wc + fr][kof];
        short8 b1 = *(const short8*)&Bs_b[wc + 16 + fr][kof];
        acc[0][0] = __builtin_amdgcn_mfma_f32_16x16x32_bf16(a0, b0, acc[0][0], 0, 0, 0);
        acc[0][1] = __builtin_amdgcn_mfma_f32_16x16x32_bf16(a0, b1, acc[0][1], 0, 0, 0);
        acc[1][0] = __builtin_amdgcn_mfma_f32_16x16x32_bf16(a1, b0, acc[1][0], 0, 0, 0);
        acc[1][1] = __builtin_amdgcn_mfma_f32_16x16x32_bf16(a1, b1, acc[1][1], 0, 0, 0);
    }

#pragma unroll
    for (int i = 0; i < 2; ++i) {
#pragma unroll
        for (int r = 0; r < 4; ++r) {
            int gr = bm + wr + i * 16 + ((l >> 4) << 2) + r;
            if (gr < M) {
                float s = dinv[gr];
#pragma unroll
                for (int j = 0; j < 2; ++j) {
                    int gc = bn + wc + j * 16 + (l & 15);
                    Cout[(size_t)gr * Ntot + gc] = f2bf(acc[i][j][r] * s);
                }
            }
        }
    }
}

// One wave per node, hs in bf16. acc = dinv[d]*(sum hs[src] + hs[d]) + b.
// OBF: store bf16 with fused ReLU (layer-1 -> layer-2 input); else fp32.
template <int C, bool OBF>
__global__ __launch_bounds__(256) void k_aggr(const unsigned short* __restrict__ hs,
                                              const int* __restrict__ srcs,
                                              const int* __restrict__ offs,
                                              const float* __restrict__ dinv,
                                              const float* __restrict__ bias,
                                              void* __restrict__ outp, int n) {
    constexpr int ROWB = C * 2;            // bf16 row bytes: 256 or 128
    constexpr int LPE  = ROWB / 16;        // lanes per row in a 1KB load
    constexpr int EPL  = 64 / LPE;         // edge rows per 1KB load
    constexpr int CHUNK = 16;              // edges per chunk
    __shared__ __align__(1024) char smem[4][CHUNK * ROWB];

    const int lane = threadIdx.x & 63;
    const int wid  = threadIdx.x >> 6;
    const int node = blockIdx.x * 4 + wid;
    if (node >= n) return;
    char* region = smem[wid];

    float2 acc = make_float2(0.f, 0.f);

    const int off = offs[node], end = offs[node + 1];
    for (int base = off; base < end; base += 64) {
        const int m = end - base;
        int p = 0;                          // pad lanes: row 0
        if (lane < m) p = srcs[base + lane];
        const int cnt = m < 64 ? m : 64;

        for (int j0 = 0; j0 < cnt; j0 += CHUNK) {
            const int cc = min(CHUNK, cnt - j0);
            const int nload = (cc + EPL - 1) / EPL;
            for (int l = 0; l < nload; ++l) {
                int e = j0 + l * EPL + (lane / LPE);     // e <= 63
                int srow = __shfl(p, e);                 // pad lanes -> row 0
                const char* ga = (const char*)hs + (size_t)srow * ROWB + (lane % LPE) * 16;
                __builtin_amdgcn_global_load_lds(
                    (const __attribute__((address_space(1))) unsigned int*)ga,
                    (__attribute__((address_space(3))) unsigned int*)(region + l * 1024),
                    16, 0, 0);
            }
            asm volatile("s_waitcnt vmcnt(0)" ::: "memory");
            __builtin_amdgcn_sched_barrier(0);

            if (C == 128) {
                for (int j = 0; j < cc; ++j) {
                    unsigned int u = *(const unsigned int*)(region + j * ROWB + lane * 4);
                    acc.x += __uint_as_float(u << 16);
                    acc.y += __uint_as_float(u & 0xffff0000u);
                }
            } else {
                const int half = lane >> 5;
                const int rounds = (cc + 1) >> 1;
                for (int r = 0; r < rounds; ++r) {
                    int e = r * 2 + half;
                    unsigned int u = *(const unsigned int*)(region + e * ROWB + (lane & 31) * 4);
                    if (e >= cc) u = 0u;
                    acc.x += __uint_as_float(u << 16);
                    acc.y += __uint_as_float(u & 0xffff0000u);
                }
            }
        }
    }

    if (C == 64) {
        acc.x += __shfl_xor(acc.x, 32);
        acc.y += __shfl_xor(acc.y, 32);
        if (lane >= 32) return;
    }
    {
        unsigned int u = *(const unsigned int*)((const char*)hs + (size_t)node * ROWB + lane * 4);
        acc.x += __uint_as_float(u << 16);
        acc.y += __uint_as_float(u & 0xffff0000u);
        float di = dinv[node];
        float2 bb = *(const float2*)&bias[lane * 2];
        float vx = fmaf(acc.x, di, bb.x);
        float vy = fmaf(acc.y, di, bb.y);
        if (OBF) {
            unsigned short* ob = (unsigned short*)outp;
            ushort2 o = make_ushort2(f2bf(fmaxf(vx, 0.f)), f2bf(fmaxf(vy, 0.f)));
            *(ushort2*)&ob[(size_t)node * C + lane * 2] = o;
        } else {
            *(float2*)&((float*)outp)[(size_t)node * C + lane * 2] = make_float2(vx, vy);
        }
    }
}

extern "C" void kernel_launch(void* const* d_in, const int* in_sizes, int n_in,
                              void* d_out, int out_size, void* d_ws, size_t ws_size,
                              hipStream_t stream) {
    const float* x  = (const float*)d_in[0];
    const int*   ei = (const int*)d_in[1];
    const float* W1 = (const float*)d_in[2];
    const float* b1 = (const float*)d_in[3];
    const float* W2 = (const float*)d_in[4];
    const float* b2 = (const float*)d_in[5];
    float* out = (float*)d_out;

    const int N = in_sizes[0] / 128;   // 50000
    const int E = in_sizes[1] / 2;     // 800000
    const int* src = ei;
    const int* dst = ei + E;
    const int NB = (N + NPB - 1) / NPB;   // 256 buckets
    const int NHB = 256;                  // histogram blocks
    const int CPB = (E + 255) / 256;      // edges per partition block

    char* wsb = (char*)d_ws;
    size_t o = 0;
    auto alloc = [&](size_t bytes, size_t align) {
        o = (o + align - 1) & ~(align - 1);
        char* p = wsb + o;
        o += bytes;
        return p;
    };
    int*   bhist_blk = (int*)alloc((size_t)NHB * NB * 4, 4);
    int*   bbase  = (int*)alloc((size_t)(NB + 1) * 4, 4);
    int*   bcur   = (int*)alloc((size_t)NB * 4, 4);
    int2*  part   = (int2*)alloc((size_t)E * 8, 8);
    int*   offs   = (int*)alloc((size_t)(N + 1) * 4, 4);
    float* dinv   = (float*)alloc((size_t)N * 4, 4);
    int*   srcs   = (int*)alloc((size_t)E * 4, 4);
    unsigned short* hs1   = (unsigned short*)alloc((size_t)N * 128 * 2, 16);
    unsigned short* hs2   = (unsigned short*)alloc((size_t)N * 64 * 2, 16);
    unsigned short* agg1b = (unsigned short*)alloc((size_t)N * 128 * 2, 16);

    // ---- CSR build (bucket-partitioned, atomic-free histogram) ----
    k_bhist<<<NHB, 256, 0, stream>>>(dst, bhist_blk, NB, E);
    k_bscan<<<1, 256, 0, stream>>>(bhist_blk, NHB, bbase, bcur, NB, E);
    k_bpart<<<256, 256, 0, stream>>>(src, dst, bcur, part, NB, E, CPB);
    k_bcsr<<<NB, 256, 0, stream>>>(part, bbase, offs, dinv, srcs, N, E);

    const int gm = (N + 63) / 64;     // 782
    const int ga = (N + 3) / 4;

    // layer 1: hs1 = bf16((x @ W1) * dinv) ; agg1b = bf16(relu(dinv*sum + b1))
    k_gemm<false><<<dim3(gm, 2), 256, 0, stream>>>(x, W1, dinv, hs1, N, 128);
    k_aggr<128, true><<<ga, 256, 0, stream>>>(hs1, srcs, offs, dinv, b1, agg1b, N);

    // layer 2: hs2 = bf16((agg1b @ W2) * dinv) ; out = dinv*sum + b2 (fp32)
    k_gemm<true><<<dim3(gm, 1), 256, 0, stream>>>(agg1b, W2, dinv, hs2, N, 64);
    k_aggr<64, false><<<ga, 256, 0, stream>>>(hs2, srcs, offs, dinv, b2, out, N);
}

// Round 16
// 136.083 us; speedup vs baseline: 1.3850x; 1.3850x over previous
//
#include <hip/hip_runtime.h>
#include <hip/hip_bf16.h>

// N_NODES=50000, N_EDGES=800000, IN=128, HID=128, OUT=64, fp32 in/out.
// Bucket-partitioned CSR build + scaled bf16 features hs = dinv*h:
//   out[d] = dinv[d]*(sum hs[src] + hs[d]) + b
// GEMM: MFMA bf16 16x16x32, 64x64 tile, K=128 fully staged (verified r12).
// aggr: per-node wave, 16-edge global_load_lds chunks (r12 best config).

#define NPB 196      // nodes per bucket
#define NBMAX 1024   // max buckets supported
#define CAP 4096     // max edges per bucket staged in LDS

using short8 = __attribute__((ext_vector_type(8))) short;
using f32x4  = __attribute__((ext_vector_type(4))) float;

__device__ __forceinline__ unsigned short f2bf(float f) {
    unsigned int u = __float_as_uint(f);
    unsigned int r = u + 0x7fffu + ((u >> 16) & 1u);   // RNE
    return (unsigned short)(r >> 16);
}

__global__ void k_zerob(int* __restrict__ p, int n) {
    int i = blockIdx.x * blockDim.x + threadIdx.x;
    if (i < n) p[i] = 0;
}

// Bucket histogram: LDS-staged, one global atomicAdd per (block,bucket).
__global__ __launch_bounds__(256) void k_bhist(const int* __restrict__ dst,
                                               int* __restrict__ bhist,
                                               int nb, int e) {
    __shared__ int hist[NBMAX];
    const int tid = threadIdx.x;
    for (int b = tid; b < nb; b += 256) hist[b] = 0;
    __syncthreads();
    for (int i = blockIdx.x * 256 + tid; i < e; i += gridDim.x * 256)
        atomicAdd(&hist[dst[i] / NPB], 1);
    __syncthreads();
    for (int b = tid; b < nb; b += 256)
        if (hist[b]) atomicAdd(&bhist[b], hist[b]);
}

// One wave: exclusive scan of nb bucket totals -> bbase, bcursor; bbase[nb]=e.
__global__ __launch_bounds__(64) void k_bscan(const int* __restrict__ bhist,
                                              int* __restrict__ bbase,
                                              int* __restrict__ bcursor,
                                              int nb, int e) {
    const int lane = threadIdx.x;
    int carry = 0;
    for (int base = 0; base < nb; base += 64) {
        int i = base + lane;
        int v = (i < nb) ? bhist[i] : 0;
        int s = v;
#pragma unroll
        for (int d = 1; d < 64; d <<= 1) {
            int u = __shfl_up(s, d);
            if (lane >= d) s += u;
        }
        int excl = carry + s - v;
        if (i < nb) { bbase[i] = excl; bcursor[i] = excl; }
        carry += __shfl(s, 63);
    }
    if (lane == 0) bbase[nb] = e;
}

// Partition edges into bucket-contiguous regions.
__global__ __launch_bounds__(256) void k_bpart(const int* __restrict__ src,
                                               const int* __restrict__ dst,
                                               int* __restrict__ bcursor,
                                               int2* __restrict__ part,
                                               int nb, int e, int cpb) {
    __shared__ int chist[NBMAX];
    __shared__ int cbase[NBMAX];
    const int tid = threadIdx.x;
    const int e0 = blockIdx.x * cpb;
    const int e1 = min(e, e0 + cpb);
    for (int b = tid; b < nb; b += 256) chist[b] = 0;
    __syncthreads();
    for (int i = e0 + tid; i < e1; i += 256)
        atomicAdd(&chist[dst[i] / NPB], 1);
    __syncthreads();
    for (int b = tid; b < nb; b += 256) {
        int c = chist[b];
        cbase[b] = c ? atomicAdd(&bcursor[b], c) : 0;
        chist[b] = 0;
    }
    __syncthreads();
    for (int i = e0 + tid; i < e1; i += 256) {
        int d = dst[i];
        int bkt = d / NPB;
        int l = atomicAdd(&chist[bkt], 1);
        part[cbase[bkt] + l] = make_int2(src[i], d);
    }
}

// One block per bucket: local counts -> local scan -> LDS-staged CSR slice.
__global__ __launch_bounds__(256) void k_bcsr(const int2* __restrict__ part,
                                              const int* __restrict__ bbase,
                                              int* __restrict__ offs,
                                              float* __restrict__ dinv,
                                              int* __restrict__ srcs,
                                              int n, int e) {
    __shared__ int cntL[256];
    __shared__ int srcsL[CAP];
    const int b = blockIdx.x;
    const int tid = threadIdx.x;
    const int eb0 = bbase[b], eb1 = bbase[b + 1];
    const int cnt = eb1 - eb0;
    const int n0 = b * NPB;
    const int npb = min(NPB, n - n0);

    if (tid < 256) cntL[tid] = 0;
    __syncthreads();
    for (int i = eb0 + tid; i < eb1; i += 256)
        atomicAdd(&cntL[part[i].y - n0], 1);
    __syncthreads();

    if (tid < 64) {
        const int lane = tid;
        int carry = 0;
        for (int base = 0; base < npb; base += 64) {
            int i = base + lane;
            int v = (i < npb) ? cntL[i] : 0;
            int s = v;
#pragma unroll
            for (int d = 1; d < 64; d <<= 1) {
                int u = __shfl_up(s, d);
                if (lane >= d) s += u;
            }
            int excl = carry + s - v;
            if (i < npb) {
                offs[n0 + i] = eb0 + excl;
                dinv[n0 + i] = rsqrtf((float)(v + 1));
                cntL[i] = excl;            // becomes the local cursor
            }
            carry += __shfl(s, 63);
        }
    }
    if (b == gridDim.x - 1 && tid == 0) offs[n] = e;
    __syncthreads();

    if (cnt <= CAP) {
        for (int i = eb0 + tid; i < eb1; i += 256) {
            int2 pr = part[i];
            int pos = atomicAdd(&cntL[pr.y - n0], 1);
            srcsL[pos] = pr.x;
        }
        __syncthreads();
        for (int i = tid; i < cnt; i += 256)
            srcs[eb0 + i] = srcsL[i];
    } else {  // safety fallback
        for (int i = eb0 + tid; i < eb1; i += 256) {
            int2 pr = part[i];
            int pos = atomicAdd(&cntL[pr.y - n0], 1);
            srcs[eb0 + pos] = pr.x;
        }
    }
}

// hs[M x Ntot] (bf16) = (A[M x 128] @ W[128 x Ntot]) * dinv[row]
// MFMA 16x16x32 bf16; 64x64 tile, 4 waves 2x2, K=128 fully staged.
template <bool SRC_BF16>
__global__ __launch_bounds__(256) void k_gemm(const void* __restrict__ A,
                                              const float* __restrict__ W,
                                              const float* __restrict__ dinv,
                                              unsigned short* __restrict__ Cout,
                                              int M, int Ntot) {
    __shared__ __align__(16) unsigned short As_b[64][136];  // [row][k]
    __shared__ __align__(16) unsigned short Bs_b[64][136];  // [col][k] (W^T)

    const int tid = threadIdx.x;
    const int bm = blockIdx.x * 64;
    const int bn = blockIdx.y * 64;

#pragma unroll
    for (int t = 0; t < 8; ++t) {
        int idx = tid + t * 256;
        int row = idx >> 5;
        int c4 = idx & 31;
        int gr = bm + row;
        ushort4 o = make_ushort4(0, 0, 0, 0);
        if (SRC_BF16) {
            if (gr < M)
                o = *(const ushort4*)&((const unsigned short*)A)[(size_t)gr * 128 + c4 * 4];
        } else {
            if (gr < M) {
                float4 f = *(const float4*)&((const float*)A)[(size_t)gr * 128 + c4 * 4];
                o = make_ushort4(f2bf(f.x), f2bf(f.y), f2bf(f.z), f2bf(f.w));
            }
        }
        *(ushort4*)&As_b[row][c4 * 4] = o;
    }

#pragma unroll
    for (int t = 0; t < 2; ++t) {
        int idx = tid + t * 256;        // 0..511
        int kb = idx >> 4;              // 0..31 -> k0 = kb*4
        int c4 = idx & 15;              // col quad
        int k0 = kb * 4;
        float4 f0 = *(const float4*)&W[(size_t)(k0 + 0) * Ntot + bn + c4 * 4];
        float4 f1 = *(const float4*)&W[(size_t)(k0 + 1) * Ntot + bn + c4 * 4];
        float4 f2 = *(const float4*)&W[(size_t)(k0 + 2) * Ntot + bn + c4 * 4];
        float4 f3 = *(const float4*)&W[(size_t)(k0 + 3) * Ntot + bn + c4 * 4];
        *(ushort4*)&Bs_b[c4 * 4 + 0][k0] =
            make_ushort4(f2bf(f0.x), f2bf(f1.x), f2bf(f2.x), f2bf(f3.x));
        *(ushort4*)&Bs_b[c4 * 4 + 1][k0] =
            make_ushort4(f2bf(f0.y), f2bf(f1.y), f2bf(f2.y), f2bf(f3.y));
        *(ushort4*)&Bs_b[c4 * 4 + 2][k0] =
            make_ushort4(f2bf(f0.z), f2bf(f1.z), f2bf(f2.z), f2bf(f3.z));
        *(ushort4*)&Bs_b[c4 * 4 + 3][k0] =
            make_ushort4(f2bf(f0.w), f2bf(f1.w), f2bf(f2.w), f2bf(f3.w));
    }
    __syncthreads();

    const int w = tid >> 6;
    const int l = tid & 63;
    const int wr = (w >> 1) * 32;
    const int wc = (w & 1) * 32;
    const int fr = l & 15;
    const int fk = (l >> 4) * 8;

    f32x4 acc[2][2] = {};

#pragma unroll
    for (int ks = 0; ks < 4; ++ks) {
        const int kof = ks * 32 + fk;
        short8 a0 = *(const short8*)&As_b[wr + fr][kof];
        short8 a1 = *(const short8*)&As_b[wr + 16 + fr][kof];
        short8 b0 = *(const short8*)&Bs_b[wc + fr][kof];
        short8 b1 = *(const short8*)&Bs_b[wc + 16 + fr][kof];
        acc[0][0] = __builtin_amdgcn_mfma_f32_16x16x32_bf16(a0, b0, acc[0][0], 0, 0, 0);
        acc[0][1] = __builtin_amdgcn_mfma_f32_16x16x32_bf16(a0, b1, acc[0][1], 0, 0, 0);
        acc[1][0] = __builtin_amdgcn_mfma_f32_16x16x32_bf16(a1, b0, acc[1][0], 0, 0, 0);
        acc[1][1] = __builtin_amdgcn_mfma_f32_16x16x32_bf16(a1, b1, acc[1][1], 0, 0, 0);
    }

#pragma unroll
    for (int i = 0; i < 2; ++i) {
#pragma unroll
        for (int r = 0; r < 4; ++r) {
            int gr = bm + wr + i * 16 + ((l >> 4) << 2) + r;
            if (gr < M) {
                float s = dinv[gr];
#pragma unroll
                for (int j = 0; j < 2; ++j) {
                    int gc = bn + wc + j * 16 + (l & 15);
                    Cout[(size_t)gr * Ntot + gc] = f2bf(acc[i][j][r] * s);
                }
            }
        }
    }
}

// One wave per node, hs in bf16. acc = dinv[d]*(sum hs[src] + hs[d]) + b.
// OBF: store bf16 with fused ReLU (layer-1 -> layer-2 input); else fp32.
template <int C, bool OBF>
__global__ __launch_bounds__(256) void k_aggr(const unsigned short* __restrict__ hs,
                                              const int* __restrict__ srcs,
                                              const int* __restrict__ offs,
                                              const float* __restrict__ dinv,
                                              const float* __restrict__ bias,
                                              void* __restrict__ outp, int n) {
    constexpr int ROWB = C * 2;            // bf16 row bytes: 256 or 128
    constexpr int LPE  = ROWB / 16;        // lanes per row in a 1KB load
    constexpr int EPL  = 64 / LPE;         // edge rows per 1KB load
    constexpr int CHUNK = 16;              // edges per chunk
    __shared__ __align__(1024) char smem[4][CHUNK * ROWB];

    const int lane = threadIdx.x & 63;
    const int wid  = threadIdx.x >> 6;
    const int node = blockIdx.x * 4 + wid;
    if (node >= n) return;
    char* region = smem[wid];

    float2 acc = make_float2(0.f, 0.f);

    const int off = offs[node], end = offs[node + 1];
    for (int base = off; base < end; base += 64) {
        const int m = end - base;
        int p = 0;                          // pad lanes: row 0
        if (lane < m) p = srcs[base + lane];
        const int cnt = m < 64 ? m : 64;

        for (int j0 = 0; j0 < cnt; j0 += CHUNK) {
            const int cc = min(CHUNK, cnt - j0);
            const int nload = (cc + EPL - 1) / EPL;
            for (int l = 0; l < nload; ++l) {
                int e = j0 + l * EPL + (lane / LPE);     // e <= 63
                int srow = __shfl(p, e);                 // pad lanes -> row 0
                const char* ga = (const char*)hs + (size_t)srow * ROWB + (lane % LPE) * 16;
                __builtin_amdgcn_global_load_lds(
                    (const __attribute__((address_space(1))) unsigned int*)ga,
                    (__attribute__((address_space(3))) unsigned int*)(region + l * 1024),
                    16, 0, 0);
            }
            asm volatile("s_waitcnt vmcnt(0)" ::: "memory");
            __builtin_amdgcn_sched_barrier(0);

            if (C == 128) {
                for (int j = 0; j < cc; ++j) {
                    unsigned int u = *(const unsigned int*)(region + j * ROWB + lane * 4);
                    acc.x += __uint_as_float(u << 16);
                    acc.y += __uint_as_float(u & 0xffff0000u);
                }
            } else {
                const int half = lane >> 5;
                const int rounds = (cc + 1) >> 1;
                for (int r = 0; r < rounds; ++r) {
                    int e = r * 2 + half;
                    unsigned int u = *(const unsigned int*)(region + e * ROWB + (lane & 31) * 4);
                    if (e >= cc) u = 0u;
                    acc.x += __uint_as_float(u << 16);
                    acc.y += __uint_as_float(u & 0xffff0000u);
                }
            }
        }
    }

    if (C == 64) {
        acc.x += __shfl_xor(acc.x, 32);
        acc.y += __shfl_xor(acc.y, 32);
        if (lane >= 32) return;
    }
    {
        unsigned int u = *(const unsigned int*)((const char*)hs + (size_t)node * ROWB + lane * 4);
        acc.x += __uint_as_float(u << 16);
        acc.y += __uint_as_float(u & 0xffff0000u);
        float di = dinv[node];
        float2 bb = *(const float2*)&bias[lane * 2];
        float vx = fmaf(acc.x, di, bb.x);
        float vy = fmaf(acc.y, di, bb.y);
        if (OBF) {
            unsigned short* ob = (unsigned short*)outp;
            ushort2 o = make_ushort2(f2bf(fmaxf(vx, 0.f)), f2bf(fmaxf(vy, 0.f)));
            *(ushort2*)&ob[(size_t)node * C + lane * 2] = o;
        } else {
            *(float2*)&((float*)outp)[(size_t)node * C + lane * 2] = make_float2(vx, vy);
        }
    }
}

extern "C" void kernel_launch(void* const* d_in, const int* in_sizes, int n_in,
                              void* d_out, int out_size, void* d_ws, size_t ws_size,
                              hipStream_t stream) {
    const float* x  = (const float*)d_in[0];
    const int*   ei = (const int*)d_in[1];
    const float* W1 = (const float*)d_in[2];
    const float* b1 = (const float*)d_in[3];
    const float* W2 = (const float*)d_in[4];
    const float* b2 = (const float*)d_in[5];
    float* out = (float*)d_out;

    const int N = in_sizes[0] / 128;   // 50000
    const int E = in_sizes[1] / 2;     // 800000
    const int* src = ei;
    const int* dst = ei + E;
    const int NB = (N + NPB - 1) / NPB;   // 256 buckets
    const int CPB = (E + 255) / 256;      // edges per partition block

    char* wsb = (char*)d_ws;
    size_t o = 0;
    auto alloc = [&](size_t bytes, size_t align) {
        o = (o + align - 1) & ~(align - 1);
        char* p = wsb + o;
        o += bytes;
        return p;
    };
    int*   bhist  = (int*)alloc((size_t)NB * 4, 4);
    int*   bbase  = (int*)alloc((size_t)(NB + 1) * 4, 4);
    int*   bcur   = (int*)alloc((size_t)NB * 4, 4);
    int2*  part   = (int2*)alloc((size_t)E * 8, 8);
    int*   offs   = (int*)alloc((size_t)(N + 1) * 4, 4);
    float* dinv   = (float*)alloc((size_t)N * 4, 4);
    int*   srcs   = (int*)alloc((size_t)E * 4, 4);
    unsigned short* hs1   = (unsigned short*)alloc((size_t)N * 128 * 2, 16);
    unsigned short* hs2   = (unsigned short*)alloc((size_t)N * 64 * 2, 16);
    unsigned short* agg1b = (unsigned short*)alloc((size_t)N * 128 * 2, 16);

    // ---- CSR build (bucket-partitioned) ----
    k_zerob<<<1, 1024, 0, stream>>>(bhist, NB);
    k_bhist<<<256, 256, 0, stream>>>(dst, bhist, NB, E);
    k_bscan<<<1, 64, 0, stream>>>(bhist, bbase, bcur, NB, E);
    k_bpart<<<256, 256, 0, stream>>>(src, dst, bcur, part, NB, E, CPB);
    k_bcsr<<<NB, 256, 0, stream>>>(part, bbase, offs, dinv, srcs, N, E);

    const int gm = (N + 63) / 64;     // 782
    const int ga = (N + 3) / 4;

    // layer 1: hs1 = bf16((x @ W1) * dinv) ; agg1b = bf16(relu(dinv*sum + b1))
    k_gemm<false><<<dim3(gm, 2), 256, 0, stream>>>(x, W1, dinv, hs1, N, 128);
    k_aggr<128, true><<<ga, 256, 0, stream>>>(hs1, srcs, offs, dinv, b1, agg1b, N);

    // layer 2: hs2 = bf16((agg1b @ W2) * dinv) ; out = dinv*sum + b2 (fp32)
    k_gemm<true><<<dim3(gm, 1), 256, 0, stream>>>(agg1b, W2, dinv, hs2, N, 64);
    k_aggr<64, false><<<ga, 256, 0, stream>>>(hs2, srcs, offs, dinv, b2, out, N);
}